// Round 6
// baseline (207.240 us; speedup 1.0000x reference)
//
#include <hip/hip_runtime.h>

// Problem constants: B=4, S=1024, H=1024, NH=16, DH=64, M=B*S=4096.

typedef __attribute__((ext_vector_type(8))) __bf16 bf16x8;
typedef __attribute__((ext_vector_type(4))) float f32x4;
typedef __attribute__((ext_vector_type(8))) unsigned short u16x8;
typedef __attribute__((ext_vector_type(4))) unsigned short u16x4;

// workspace layout (ushort element offsets)
#define XQ_OFF 0u
#define XK_OFF 4194304u
#define XV_OFF 8388608u
#define WQ_OFF 12582912u
#define WK_OFF 13631488u
#define WV_OFF 14680064u
#define QP_OFF 15728640u
#define KP_OFF 19922944u
#define VT_OFF 24117248u   // V projection written DIRECTLY transposed: [(b*16+h)*64+dh][s]
// total = 28311552 ushorts = 54 MiB

__device__ __forceinline__ unsigned short f2bf(float f) {
  union { float f; unsigned int u; } c; c.f = f;
  return (unsigned short)((c.u + 0x7fffu + ((c.u >> 16) & 1u)) >> 16);  // RNE
}

// ---------------- fp32 -> bf16 conversion of inputs ----------------
__global__ __launch_bounds__(256) void cvt_kernel(
    const float* __restrict__ q, const float* __restrict__ k, const float* __restrict__ v,
    const float* __restrict__ wq, const float* __restrict__ wk, const float* __restrict__ wv,
    unsigned short* __restrict__ ws) {
  const int z = blockIdx.y;
  const float* src; unsigned short* dst; int n;
  switch (z) {
    case 0: src = q;  dst = ws + XQ_OFF; n = 4194304; break;
    case 1: src = k;  dst = ws + XK_OFF; n = 4194304; break;
    case 2: src = v;  dst = ws + XV_OFF; n = 4194304; break;
    case 3: src = wq; dst = ws + WQ_OFF; n = 1048576; break;
    case 4: src = wk; dst = ws + WK_OFF; n = 1048576; break;
    default: src = wv; dst = ws + WV_OFF; n = 1048576; break;
  }
  const int i8 = (blockIdx.x * 256 + threadIdx.x) * 8;
  if (i8 >= n) return;
  const float4 f0 = *(const float4*)(src + i8);
  const float4 f1 = *(const float4*)(src + i8 + 4);
  u16x8 r;
  r[0] = f2bf(f0.x); r[1] = f2bf(f0.y); r[2] = f2bf(f0.z); r[3] = f2bf(f0.w);
  r[4] = f2bf(f1.x); r[5] = f2bf(f1.y); r[6] = f2bf(f1.z); r[7] = f2bf(f1.w);
  *(u16x8*)(dst + i8) = r;
}

// ---------------- fused projection GEMMs: P = relu(X @ W^T + b), bf16 out ----------------
// blockIdx.z selects {Q,K,V}. 128x128 tile, BK=32, 4 waves x 64x64.
// Epilogue repacks each wave's 64x64 C-block through per-wave LDS so global stores
// are coalesced b128. z==2 writes the TRANSPOSED layout directly (VT) -> no vtrans kernel.
__global__ __launch_bounds__(256) void proj_gemm(
    unsigned short* __restrict__ ws,
    const float* __restrict__ bq, const float* __restrict__ bk, const float* __restrict__ bv) {
  __shared__ unsigned short smem[18432];  // k-loop: As[0:4096], Bs[4096:8192]; epilogue: T[w*4608]
  unsigned short* As = smem;
  unsigned short* Bs = smem + 4096;
  const int z = blockIdx.z;
  const unsigned short* X = ws + (z == 0 ? XQ_OFF : z == 1 ? XK_OFF : XV_OFF);
  const unsigned short* W = ws + (z == 0 ? WQ_OFF : z == 1 ? WK_OFF : WV_OFF);
  unsigned short* P = ws + (z == 0 ? QP_OFF : z == 1 ? KP_OFF : VT_OFF);
  const float* bias = z == 0 ? bq : z == 1 ? bk : bv;

  const int tid  = threadIdx.x;
  const int lane = tid & 63;
  const int w    = tid >> 6;
  const int quad = lane >> 4;
  const int l15  = lane & 15;
  const int wr = w >> 1, wc = w & 1;
  const int m0 = blockIdx.y * 128;
  const int n0 = blockIdx.x * 128;

  f32x4 acc[4][4];
#pragma unroll
  for (int i = 0; i < 4; ++i)
#pragma unroll
    for (int j = 0; j < 4; ++j) acc[i][j] = f32x4{0.f, 0.f, 0.f, 0.f};

  for (int kt = 0; kt < 32; ++kt) {
    const int k0 = kt * 32;
#pragma unroll
    for (int pass = 0; pass < 2; ++pass) {
      const int c   = pass * 256 + tid;
      const int row = c >> 2;
      const int kc  = (c & 3) * 8;
      const unsigned short* ga = X + (size_t)(m0 + row) * 1024 + k0 + kc;
      const unsigned short* gb = W + (size_t)(n0 + row) * 1024 + k0 + kc;
      unsigned short* la = &As[(pass * 256 + w * 64) * 8];
      unsigned short* lb = &Bs[(pass * 256 + w * 64) * 8];
      __builtin_amdgcn_global_load_lds((const __attribute__((address_space(1))) void*)ga,
                                       (__attribute__((address_space(3))) void*)la, 16, 0, 0);
      __builtin_amdgcn_global_load_lds((const __attribute__((address_space(1))) void*)gb,
                                       (__attribute__((address_space(3))) void*)lb, 16, 0, 0);
    }
    __syncthreads();
    bf16x8 af[4], bfv[4];
#pragma unroll
    for (int mi = 0; mi < 4; ++mi)
      af[mi] = *(const bf16x8*)&As[(wr * 64 + mi * 16 + l15) * 32 + quad * 8];
#pragma unroll
    for (int ni = 0; ni < 4; ++ni)
      bfv[ni] = *(const bf16x8*)&Bs[(wc * 64 + ni * 16 + l15) * 32 + quad * 8];
#pragma unroll
    for (int mi = 0; mi < 4; ++mi)
#pragma unroll
      for (int ni = 0; ni < 4; ++ni)
        acc[mi][ni] = __builtin_amdgcn_mfma_f32_16x16x32_bf16(af[mi], bfv[ni], acc[mi][ni], 0, 0, 0);
    __syncthreads();
  }

  // ---- epilogue: per-wave 64x64 repack through LDS (As/Bs dead after last barrier) ----
  unsigned short* Tw = smem + w * 4608;  // 64 * 72
  if (z != 2) {
    // row-major out. T[row][col] (stride 72): u16 scatter in, b128 out.
#pragma unroll
    for (int mi = 0; mi < 4; ++mi)
#pragma unroll
      for (int ni = 0; ni < 4; ++ni) {
        const float bvv = bias[n0 + wc * 64 + ni * 16 + l15];
#pragma unroll
        for (int r = 0; r < 4; ++r) {
          float v = acc[mi][ni][r] + bvv;
          v = v > 0.f ? v : 0.f;
          Tw[(mi * 16 + quad * 4 + r) * 72 + ni * 16 + l15] = f2bf(v);
        }
      }
    const int row0 = m0 + wr * 64;
    const int colb = n0 + wc * 64;
#pragma unroll
    for (int i = 0; i < 8; ++i) {
      const int rr = i * 8 + (lane >> 3);
      const int cc = (lane & 7) * 8;
      *(u16x8*)&P[(size_t)(row0 + rr) * 1024 + colb + cc] = *(const u16x8*)&Tw[rr * 72 + cc];
    }
  } else {
    // transposed out (VT[(b*16+h)*64+dh][s]). T[col][row]: b64 in, b128 out.
#pragma unroll
    for (int mi = 0; mi < 4; ++mi)
#pragma unroll
      for (int ni = 0; ni < 4; ++ni) {
        const float bvv = bias[n0 + wc * 64 + ni * 16 + l15];
        u16x4 pk;
#pragma unroll
        for (int r = 0; r < 4; ++r) {
          float v = acc[mi][ni][r] + bvv;
          v = v > 0.f ? v : 0.f;
          pk[r] = f2bf(v);
        }
        *(u16x4*)&Tw[(ni * 16 + l15) * 72 + mi * 16 + quad * 4] = pk;
      }
    const int h2 = (n0 >> 6) + wc;        // head index
    const int bb = m0 >> 10;              // batch
    const int s0 = (m0 & 1023) + wr * 64; // s within batch
#pragma unroll
    for (int i = 0; i < 8; ++i) {
      const int rr = i * 8 + (lane >> 3);  // dh
      const int cc = (lane & 7) * 8;       // s chunk
      *(u16x8*)&P[((size_t)(bb * 16 + h2) * 64 + rr) * 1024 + s0 + cc] =
          *(const u16x8*)&Tw[rr * 72 + cc];
    }
  }
}

// ---------------- fused flash attention + mask + residual ----------------
// grid (8, NH, B), block 256 (4 waves). Wave w owns 32 q rows (2 m-subtiles):
// q0w = blockIdx.x*128 + w*32  [r5 BUG: grid.x was 4 -> half of S uncovered].
// S^T = K.Q^T via operand swap: lane holds 4 CONSECUTIVE keys of ONE q -> P packs to
// b64 LDS writes; lsum is one scalar/lane. Kt/Vt staged by swizzled global_load_lds
// (chunk ^= row&7) -> no ds_writes, uniform-bank b128 fragment reads.
__global__ __launch_bounds__(256) void attn_kernel(
    const unsigned short* __restrict__ QP, const unsigned short* __restrict__ KP,
    const unsigned short* __restrict__ VT, const float* __restrict__ masks,
    const float* __restrict__ query, float* __restrict__ out) {
  __shared__ unsigned short Kt[64 * 64];     // [key][dh], chunk-swizzled, no pad (DMA dest)
  __shared__ unsigned short Vt[64 * 64];     // [dh][key], chunk-swizzled, no pad (DMA dest)
  __shared__ unsigned short Pl[4][32 * 72];  // per-wave P [q][key], padded
  const int tid  = threadIdx.x;
  const int lane = tid & 63;
  const int w    = tid >> 6;
  const int quad = lane >> 4;
  const int l15  = lane & 15;
  const int b = blockIdx.z, h = blockIdx.y;
  const int q0w = blockIdx.x * 128 + w * 32;
  const size_t base = (size_t)b * 1024 * 1024;
  const int bh = b * 16 + h;

  // Q fragments (B-operand; layout identical to A: lane n=l15, k=quad*8+j)
  bf16x8 qf[2][2];
#pragma unroll
  for (int mt = 0; mt < 2; ++mt)
#pragma unroll
    for (int kk = 0; kk < 2; ++kk)
      qf[mt][kk] = *(const bf16x8*)&QP[base + (size_t)(q0w + mt * 16 + l15) * 1024 +
                                       h * 64 + kk * 32 + quad * 8];

  f32x4 o[2][4];
  float lsum[2] = {0.f, 0.f};
#pragma unroll
  for (int mt = 0; mt < 2; ++mt)
#pragma unroll
    for (int nd = 0; nd < 4; ++nd) o[mt][nd] = f32x4{0.f, 0.f, 0.f, 0.f};

  const int r_st = lane >> 3;   // row within 8-row staging group
  const int pc   = lane & 7;    // physical 16B chunk
  const int swz  = l15 & 7;     // fragment-read swizzle key
  const float cvt = 0.18033688011112042f;  // (1/sqrt(64)) * log2(e)

  for (int kb = 0; kb < 16; ++kb) {
    const int key0 = kb * 64;
#pragma unroll
    for (int t = 0; t < 2; ++t) {
      const int rowk = (w * 2 + t) * 8 + r_st;
      const int lc   = pc ^ (rowk & 7);        // logical chunk for this lane's slot
      const unsigned short* gk = &KP[base + (size_t)(key0 + rowk) * 1024 + h * 64 + lc * 8];
      const unsigned short* gv = &VT[((size_t)bh * 64 + rowk) * 1024 + key0 + lc * 8];
      __builtin_amdgcn_global_load_lds((const __attribute__((address_space(1))) void*)gk,
                                       (__attribute__((address_space(3))) void*)&Kt[(w * 2 + t) * 512],
                                       16, 0, 0);
      __builtin_amdgcn_global_load_lds((const __attribute__((address_space(1))) void*)gv,
                                       (__attribute__((address_space(3))) void*)&Vt[(w * 2 + t) * 512],
                                       16, 0, 0);
    }
    __syncthreads();

    // hoisted K fragments (A-operand): row=key=ni*16+l15, chunk=(kk*4+quad)^swz
    bf16x8 kf[2][4];
#pragma unroll
    for (int kk = 0; kk < 2; ++kk)
#pragma unroll
      for (int ni = 0; ni < 4; ++ni)
        kf[kk][ni] = *(const bf16x8*)&Kt[(ni * 16 + l15) * 64 + ((kk * 4 + quad) ^ swz) * 8];

    // S^T = K.Q^T per m-subtile; C-layout: row=key=quad*4+reg(+16ni), col=q=l15
#pragma unroll
    for (int mt = 0; mt < 2; ++mt) {
      f32x4 st[4];
#pragma unroll
      for (int ni = 0; ni < 4; ++ni) st[ni] = f32x4{0.f, 0.f, 0.f, 0.f};
#pragma unroll
      for (int kk = 0; kk < 2; ++kk)
#pragma unroll
        for (int ni = 0; ni < 4; ++ni)
          st[ni] = __builtin_amdgcn_mfma_f32_16x16x32_bf16(kf[kk][ni], qf[mt][kk], st[ni], 0, 0, 0);
      float ls = 0.f;
#pragma unroll
      for (int ni = 0; ni < 4; ++ni) {
        u16x4 pk;
#pragma unroll
        for (int r = 0; r < 4; ++r) {
          const float p = exp2f(st[ni][r] * cvt - 8.0f);  // fixed shift, exact (scores>=0)
          ls += p;
          pk[r] = f2bf(p);
        }
        *(u16x4*)&Pl[w][(mt * 16 + l15) * 72 + ni * 16 + quad * 4] = pk;
      }
      lsum[mt] += ls;
    }

    // O += P.V : pa (A) from Pl, vf (B) from swizzled Vt
#pragma unroll
    for (int kk = 0; kk < 2; ++kk) {
      bf16x8 pa[2];
#pragma unroll
      for (int mt = 0; mt < 2; ++mt)
        pa[mt] = *(const bf16x8*)&Pl[w][(mt * 16 + l15) * 72 + kk * 32 + quad * 8];
#pragma unroll
      for (int nd = 0; nd < 4; ++nd) {
        bf16x8 vf = *(const bf16x8*)&Vt[(nd * 16 + l15) * 64 + ((kk * 4 + quad) ^ swz) * 8];
#pragma unroll
        for (int mt = 0; mt < 2; ++mt)
          o[mt][nd] = __builtin_amdgcn_mfma_f32_16x16x32_bf16(pa[mt], vf, o[mt][nd], 0, 0, 0);
      }
    }
    __syncthreads();
  }

  // reduce lsum across quads (lanes l15 hold q=l15 partials in all 4 quads)
#pragma unroll
  for (int mt = 0; mt < 2; ++mt) {
    lsum[mt] += __shfl_xor(lsum[mt], 16);
    lsum[mt] += __shfl_xor(lsum[mt], 32);
  }

  // epilogue: out = mask[q] * O / l + query
#pragma unroll
  for (int mt = 0; mt < 2; ++mt)
#pragma unroll
    for (int r = 0; r < 4; ++r) {
      const int rq = quad * 4 + r;                      // q-local of this acc reg
      const float ls = __shfl(lsum[mt], (lane & 48) | rq);
      const int row = q0w + mt * 16 + rq;
      const float scale = masks[b * 1024 + row] / ls;
#pragma unroll
      for (int nd = 0; nd < 4; ++nd) {
        const int col = h * 64 + nd * 16 + l15;
        const size_t gi = base + (size_t)row * 1024 + col;
        out[gi] = o[mt][nd][r] * scale + query[gi];
      }
    }
}

extern "C" void kernel_launch(void* const* d_in, const int* in_sizes, int n_in,
                              void* d_out, int out_size, void* d_ws, size_t ws_size,
                              hipStream_t stream) {
  const float* q     = (const float*)d_in[0];
  const float* k     = (const float*)d_in[1];
  const float* v     = (const float*)d_in[2];
  const float* masks = (const float*)d_in[3];
  const float* Wq    = (const float*)d_in[4];
  const float* bq    = (const float*)d_in[5];
  const float* Wk    = (const float*)d_in[6];
  const float* bk    = (const float*)d_in[7];
  const float* Wv    = (const float*)d_in[8];
  const float* bv    = (const float*)d_in[9];
  float* out = (float*)d_out;
  unsigned short* ws = (unsigned short*)d_ws;

  cvt_kernel<<<dim3(2048, 6), 256, 0, stream>>>(q, k, v, Wq, Wk, Wv, ws);
  proj_gemm<<<dim3(8, 32, 3), 256, 0, stream>>>(ws, bq, bk, bv);
  attn_kernel<<<dim3(8, 16, 4), 256, 0, stream>>>(ws + QP_OFF, ws + KP_OFF, ws + VT_OFF,
                                                  masks, q, out);
}